// Round 4
// baseline (503.012 us; speedup 1.0000x reference)
//
#include <hip/hip_runtime.h>
#include <cstdint>
#include <cstddef>

// Problem constants: B=4, S=1024, D=1024, H=16, DK=64, DV=32. FP32 I/O.
#define BB 4
#define SS 1024
#define DD 1024
#define HH 16
#define DKK 64
#define DVV 32
#define LOG2E 1.44269504088896340736f

typedef __bf16 bf16_t;
typedef __bf16 bf16x8 __attribute__((ext_vector_type(8)));
typedef float f32x4 __attribute__((ext_vector_type(4)));

// load 8 consecutive fp32, convert to 8 bf16 (RNE via __bf16 cast)
__device__ inline bf16x8 cvt8(const float* __restrict__ s) {
  float4 a = *(const float4*)s;
  float4 b = *(const float4*)(s + 4);
  bf16x8 r;
  r[0] = (__bf16)a.x; r[1] = (__bf16)a.y; r[2] = (__bf16)a.z; r[3] = (__bf16)a.w;
  r[4] = (__bf16)b.x; r[5] = (__bf16)b.y; r[6] = (__bf16)b.z; r[7] = (__bf16)b.w;
  return r;
}

// ---------------------------------------------------------------------------
// Transpose + cvt: dst[h][n][m] = (bf16) src[h][m][n].
// grid (ceil(N/64), M/64, H), 256 threads. M % 64 == 0; N = 1024/64/32.
// ---------------------------------------------------------------------------
__global__ __launch_bounds__(256) void transpose_cvt_kernel(
    const float* __restrict__ src, bf16_t* __restrict__ dst,
    int M, int N, size_t srcStride, size_t dstStride) {
  __shared__ __align__(16) bf16_t T[64][72];
  const int tid = threadIdx.x;
  const int n0 = blockIdx.x * 64, m0 = blockIdx.y * 64;
  const float* s = src + (size_t)blockIdx.z * srcStride;
  bf16_t* d = dst + (size_t)blockIdx.z * dstStride;
  const int rr = tid >> 3, c8 = (tid & 7) * 8;

  if (n0 + c8 < N) {
#pragma unroll
    for (int mm = rr; mm < 64; mm += 32) {
      const float* p = s + (size_t)(m0 + mm) * N + n0 + c8;
      float4 a = *(const float4*)p;
      float4 b = *(const float4*)(p + 4);
      T[c8 + 0][mm] = (__bf16)a.x; T[c8 + 1][mm] = (__bf16)a.y;
      T[c8 + 2][mm] = (__bf16)a.z; T[c8 + 3][mm] = (__bf16)a.w;
      T[c8 + 4][mm] = (__bf16)b.x; T[c8 + 5][mm] = (__bf16)b.y;
      T[c8 + 6][mm] = (__bf16)b.z; T[c8 + 7][mm] = (__bf16)b.w;
    }
  }
  __syncthreads();
#pragma unroll
  for (int rn = rr; rn < 64; rn += 32) {
    if (n0 + rn < N)
      *(uint4*)(d + (size_t)(n0 + rn) * M + m0 + c8) = *(uint4*)&T[rn][c8];
  }
}

// ---------------------------------------------------------------------------
// QKV projection: C[4096,2560] = X[4096,1024](fp32->bf16) @ WcatT^T + bias.
// Epilogue: Q'=(q+bq)/8 -> Qw[B,H,S,DK] bf16; K -> Kw; V -> VT[B,H,DV,S].
// grid (64, 40), 256 threads.
// ---------------------------------------------------------------------------
__global__ __launch_bounds__(256) void qkv_gemm_kernel(
    const float* __restrict__ X, const bf16_t* __restrict__ WT,
    const float* __restrict__ bq, const float* __restrict__ bk,
    const float* __restrict__ bv,
    bf16_t* __restrict__ Qw, bf16_t* __restrict__ Kw, bf16_t* __restrict__ VT) {
  __shared__ __align__(16) bf16_t As[64][72];
  __shared__ __align__(16) bf16_t Bs[64][72];
  const int m0 = blockIdx.x * 64;
  const int n0 = blockIdx.y * 64;
  const int tid = threadIdx.x;
  const int wave = tid >> 6;
  const int lane = tid & 63;
  const int g = lane >> 4;
  const int ln = lane & 15;
  const int r = tid >> 3;
  const int c8 = (tid & 7) * 8;

  f32x4 acc[4] = {};

  for (int k0 = 0; k0 < 1024; k0 += 64) {
    *(bf16x8*)&As[r][c8]      = cvt8(X + (size_t)(m0 + r) * 1024 + k0 + c8);
    *(bf16x8*)&As[r + 32][c8] = cvt8(X + (size_t)(m0 + r + 32) * 1024 + k0 + c8);
    *(uint4*)&Bs[r][c8]      = *(const uint4*)(WT + (size_t)(n0 + r) * 1024 + k0 + c8);
    *(uint4*)&Bs[r + 32][c8] = *(const uint4*)(WT + (size_t)(n0 + r + 32) * 1024 + k0 + c8);
    __syncthreads();
#pragma unroll
    for (int ks = 0; ks < 2; ks++) {
      bf16x8 a = *(const bf16x8*)&As[wave * 16 + ln][ks * 32 + g * 8];
#pragma unroll
      for (int ns = 0; ns < 4; ns++) {
        bf16x8 b = *(const bf16x8*)&Bs[ns * 16 + ln][ks * 32 + g * 8];
        acc[ns] = __builtin_amdgcn_mfma_f32_16x16x32_bf16(a, b, acc[ns], 0, 0, 0);
      }
    }
    __syncthreads();
  }

#pragma unroll
  for (int ns = 0; ns < 4; ns++) {
    int c = n0 + ns * 16 + ln;
    float bias = (c < 1024) ? bq[c] : (c < 2048 ? bk[c - 1024] : bv[c - 2048]);
#pragma unroll
    for (int i = 0; i < 4; i++) {
      int m = m0 + wave * 16 + g * 4 + i;
      float v = acc[ns][i] + bias;
      int b_ = m >> 10, s_ = m & 1023;
      if (c < 1024) {
        int h = c >> 6, k = c & 63;
        Qw[(((size_t)(b_ * HH + h)) * SS + s_) * DKK + k] = (__bf16)(v * 0.125f);
      } else if (c < 2048) {
        int c2 = c - 1024;
        int h = c2 >> 6, k = c2 & 63;
        Kw[(((size_t)(b_ * HH + h)) * SS + s_) * DKK + k] = (__bf16)v;
      } else {
        int c2 = c - 2048;
        int h = c2 >> 5, vv = c2 & 31;
        VT[(((size_t)(b_ * HH + h)) * DVV + vv) * SS + s_] = (__bf16)v;
      }
    }
  }
}

// ---------------------------------------------------------------------------
// Scores + softmax -> fp32 weights into d_out. Two-pass online softmax.
// grid (16, 64), 256 threads; each wave owns 16 rows.
// ---------------------------------------------------------------------------
__global__ __launch_bounds__(256) void attn_softmax_kernel(
    const bf16_t* __restrict__ Qw, const bf16_t* __restrict__ Kw,
    float* __restrict__ Wout) {
  __shared__ __align__(16) bf16_t Qs[64][72];
  __shared__ __align__(16) bf16_t Ks[64][72];
  const int bh = blockIdx.y;
  const int m0 = blockIdx.x * 64;
  const int tid = threadIdx.x;
  const int wave = tid >> 6;
  const int lane = tid & 63;
  const int g = lane >> 4;
  const int ln = lane & 15;
  const int r = tid >> 3;
  const int c8 = (tid & 7) * 8;

  const bf16_t* Qbase = Qw + (size_t)bh * SS * DKK;
  const bf16_t* Kbase = Kw + (size_t)bh * SS * DKK;

  *(uint4*)&Qs[r][c8]      = *(const uint4*)(Qbase + (size_t)(m0 + r) * DKK + c8);
  *(uint4*)&Qs[r + 32][c8] = *(const uint4*)(Qbase + (size_t)(m0 + r + 32) * DKK + c8);
  __syncthreads();

  float mrun[4] = {-1e30f, -1e30f, -1e30f, -1e30f};
  float lrun[4] = {0.f, 0.f, 0.f, 0.f};

  for (int jt = 0; jt < 16; jt++) {
    *(uint4*)&Ks[r][c8]      = *(const uint4*)(Kbase + (size_t)(jt * 64 + r) * DKK + c8);
    *(uint4*)&Ks[r + 32][c8] = *(const uint4*)(Kbase + (size_t)(jt * 64 + r + 32) * DKK + c8);
    __syncthreads();
    f32x4 acc[4] = {};
#pragma unroll
    for (int ks = 0; ks < 2; ks++) {
      bf16x8 a = *(const bf16x8*)&Qs[wave * 16 + ln][ks * 32 + g * 8];
#pragma unroll
      for (int ns = 0; ns < 4; ns++) {
        bf16x8 b = *(const bf16x8*)&Ks[ns * 16 + ln][ks * 32 + g * 8];
        acc[ns] = __builtin_amdgcn_mfma_f32_16x16x32_bf16(a, b, acc[ns], 0, 0, 0);
      }
    }
#pragma unroll
    for (int ns = 0; ns < 4; ns++) {
#pragma unroll
      for (int i = 0; i < 4; i++) {
        float p = acc[ns][i] * LOG2E;
        float mo = mrun[i];
        float mn = fmaxf(mo, p);
        lrun[i] = lrun[i] * exp2f(mo - mn) + exp2f(p - mn);
        mrun[i] = mn;
      }
    }
    __syncthreads();
  }

  // merge (m,l) across the 16 lanes sharing each row
#pragma unroll
  for (int i = 0; i < 4; i++) {
    float m = mrun[i], l = lrun[i];
#pragma unroll
    for (int d = 1; d < 16; d <<= 1) {
      float om = __shfl_xor(m, d);
      float ol = __shfl_xor(l, d);
      float nm = fmaxf(m, om);
      l = l * exp2f(m - nm) + ol * exp2f(om - nm);
      m = nm;
    }
    mrun[i] = m;
    lrun[i] = 1.0f / l;
  }

  // Pass B: recompute, write normalized fp32 weights
  float* wbase = Wout + (size_t)bh * SS * SS;
  for (int jt = 0; jt < 16; jt++) {
    *(uint4*)&Ks[r][c8]      = *(const uint4*)(Kbase + (size_t)(jt * 64 + r) * DKK + c8);
    *(uint4*)&Ks[r + 32][c8] = *(const uint4*)(Kbase + (size_t)(jt * 64 + r + 32) * DKK + c8);
    __syncthreads();
    f32x4 acc[4] = {};
#pragma unroll
    for (int ks = 0; ks < 2; ks++) {
      bf16x8 a = *(const bf16x8*)&Qs[wave * 16 + ln][ks * 32 + g * 8];
#pragma unroll
      for (int ns = 0; ns < 4; ns++) {
        bf16x8 b = *(const bf16x8*)&Ks[ns * 16 + ln][ks * 32 + g * 8];
        acc[ns] = __builtin_amdgcn_mfma_f32_16x16x32_bf16(a, b, acc[ns], 0, 0, 0);
      }
    }
#pragma unroll
    for (int ns = 0; ns < 4; ns++) {
      int col = jt * 64 + ns * 16 + ln;
#pragma unroll
      for (int i = 0; i < 4; i++) {
        int row = m0 + wave * 16 + g * 4 + i;
        wbase[(size_t)row * SS + col] =
            exp2f(acc[ns][i] * LOG2E - mrun[i]) * lrun[i];
      }
    }
    __syncthreads();
  }
}

// ---------------------------------------------------------------------------
// PV: O = weights(fp32->bf16) @ V per (b,h). concat[B*S, H*DV] bf16.
// grid (16, 64), 256 threads.
// ---------------------------------------------------------------------------
__global__ __launch_bounds__(256) void av_gemm_kernel(
    const float* __restrict__ Wts, const bf16_t* __restrict__ VT,
    bf16_t* __restrict__ concat) {
  __shared__ __align__(16) bf16_t As[64][72];
  __shared__ __align__(16) bf16_t Bs[32][72];
  const int bh = blockIdx.y;
  const int b_ = bh >> 4, h = bh & 15;
  const int m0 = blockIdx.x * 64;
  const int tid = threadIdx.x;
  const int wave = tid >> 6;
  const int lane = tid & 63;
  const int g = lane >> 4;
  const int ln = lane & 15;
  const int r = tid >> 3;
  const int c8 = (tid & 7) * 8;

  const float* wbase = Wts + (size_t)bh * SS * SS;
  const bf16_t* vbase = VT + (size_t)bh * DVV * SS;

  f32x4 acc[2] = {};

  for (int k0 = 0; k0 < 1024; k0 += 64) {
    *(bf16x8*)&As[r][c8]      = cvt8(wbase + (size_t)(m0 + r) * SS + k0 + c8);
    *(bf16x8*)&As[r + 32][c8] = cvt8(wbase + (size_t)(m0 + r + 32) * SS + k0 + c8);
    *(uint4*)&Bs[r][c8]       = *(const uint4*)(vbase + (size_t)r * SS + k0 + c8);
    __syncthreads();
#pragma unroll
    for (int ks = 0; ks < 2; ks++) {
      bf16x8 a = *(const bf16x8*)&As[wave * 16 + ln][ks * 32 + g * 8];
#pragma unroll
      for (int ns = 0; ns < 2; ns++) {
        bf16x8 b = *(const bf16x8*)&Bs[ns * 16 + ln][ks * 32 + g * 8];
        acc[ns] = __builtin_amdgcn_mfma_f32_16x16x32_bf16(a, b, acc[ns], 0, 0, 0);
      }
    }
    __syncthreads();
  }

#pragma unroll
  for (int ns = 0; ns < 2; ns++) {
    int col = ns * 16 + ln;
#pragma unroll
    for (int i = 0; i < 4; i++) {
      int s_ = m0 + wave * 16 + g * 4 + i;
      concat[((size_t)(b_ * SS + s_)) * (HH * DVV) + h * DVV + col] =
          (__bf16)acc[ns][i];
    }
  }
}

// ---------------------------------------------------------------------------
// Output projection: out = concat @ WoT^T + bo -> fp32 d_out[0 : B*S*D].
// grid (64, 16), 256 threads. K = 512.
// ---------------------------------------------------------------------------
__global__ __launch_bounds__(256) void out_gemm_kernel(
    const bf16_t* __restrict__ Cc, const bf16_t* __restrict__ WoT,
    const float* __restrict__ bo, float* __restrict__ Out) {
  __shared__ __align__(16) bf16_t As[64][72];
  __shared__ __align__(16) bf16_t Bs[64][72];
  const int m0 = blockIdx.x * 64;
  const int n0 = blockIdx.y * 64;
  const int tid = threadIdx.x;
  const int wave = tid >> 6;
  const int lane = tid & 63;
  const int g = lane >> 4;
  const int ln = lane & 15;
  const int r = tid >> 3;
  const int c8 = (tid & 7) * 8;

  f32x4 acc[4] = {};

  for (int k0 = 0; k0 < 512; k0 += 64) {
    *(uint4*)&As[r][c8]      = *(const uint4*)(Cc  + (size_t)(m0 + r) * 512 + k0 + c8);
    *(uint4*)&As[r + 32][c8] = *(const uint4*)(Cc  + (size_t)(m0 + r + 32) * 512 + k0 + c8);
    *(uint4*)&Bs[r][c8]      = *(const uint4*)(WoT + (size_t)(n0 + r) * 512 + k0 + c8);
    *(uint4*)&Bs[r + 32][c8] = *(const uint4*)(WoT + (size_t)(n0 + r + 32) * 512 + k0 + c8);
    __syncthreads();
#pragma unroll
    for (int ks = 0; ks < 2; ks++) {
      bf16x8 a = *(const bf16x8*)&As[wave * 16 + ln][ks * 32 + g * 8];
#pragma unroll
      for (int ns = 0; ns < 4; ns++) {
        bf16x8 b = *(const bf16x8*)&Bs[ns * 16 + ln][ks * 32 + g * 8];
        acc[ns] = __builtin_amdgcn_mfma_f32_16x16x32_bf16(a, b, acc[ns], 0, 0, 0);
      }
    }
    __syncthreads();
  }

#pragma unroll
  for (int ns = 0; ns < 4; ns++) {
    int col = n0 + ns * 16 + ln;
    float bias = bo[col];
#pragma unroll
    for (int i = 0; i < 4; i++) {
      int m = m0 + wave * 16 + g * 4 + i;
      Out[(size_t)m * DD + col] = acc[ns][i] + bias;
    }
  }
}

// ---------------------------------------------------------------------------
extern "C" void kernel_launch(void* const* d_in, const int* in_sizes, int n_in,
                              void* d_out, int out_size, void* d_ws, size_t ws_size,
                              hipStream_t stream) {
  const float* x  = (const float*)d_in[0];
  const float* Wq = (const float*)d_in[1];
  const float* bq = (const float*)d_in[2];
  const float* Wk = (const float*)d_in[3];
  const float* bk = (const float*)d_in[4];
  const float* Wv = (const float*)d_in[5];
  const float* bv = (const float*)d_in[6];
  const float* Wo = (const float*)d_in[7];
  const float* bo = (const float*)d_in[8];

  float* out = (float*)d_out;
  float* weights_out = out + (size_t)BB * SS * DD;   // second tuple element

  // workspace (bf16, all 16B-aligned offsets); total ~30.4 MB
  char* ws = (char*)d_ws;
  bf16_t* WcatT = (bf16_t*)ws;  ws += (size_t)2560 * 1024 * 2;       // 5 MB
  bf16_t* WoT   = (bf16_t*)ws;  ws += (size_t)1024 * 512 * 2;        // 1 MB
  bf16_t* Qw    = (bf16_t*)ws;  ws += (size_t)BB * HH * SS * DKK * 2; // 8 MB
  bf16_t* Kw    = (bf16_t*)ws;  ws += (size_t)BB * HH * SS * DKK * 2; // 8 MB
  bf16_t* VT    = (bf16_t*)ws;  ws += (size_t)BB * HH * DVV * SS * 2; // 4 MB
  bf16_t* concat = (bf16_t*)ws;                                       // 4 MB

  // Weight repacks (fp32 -> bf16, transposed)
  transpose_cvt_kernel<<<dim3(1, 16, 16), 256, 0, stream>>>(
      Wq, WcatT,                     1024, 64, (size_t)1024 * 64, (size_t)64 * 1024);
  transpose_cvt_kernel<<<dim3(1, 16, 16), 256, 0, stream>>>(
      Wk, WcatT + (size_t)1024 * 1024, 1024, 64, (size_t)1024 * 64, (size_t)64 * 1024);
  transpose_cvt_kernel<<<dim3(1, 16, 16), 256, 0, stream>>>(
      Wv, WcatT + (size_t)2048 * 1024, 1024, 32, (size_t)1024 * 32, (size_t)32 * 1024);
  transpose_cvt_kernel<<<dim3(16, 8, 1), 256, 0, stream>>>(
      Wo, WoT, 512, 1024, 0, 0);

  qkv_gemm_kernel<<<dim3(64, 40), 256, 0, stream>>>(
      x, WcatT, bq, bk, bv, Qw, Kw, VT);
  attn_softmax_kernel<<<dim3(16, 64), 256, 0, stream>>>(Qw, Kw, weights_out);
  av_gemm_kernel<<<dim3(16, 64), 256, 0, stream>>>(weights_out, VT, concat);
  out_gemm_kernel<<<dim3(64, 16), 256, 0, stream>>>(concat, WoT, bo, out);
}